// Round 2
// baseline (1057.611 us; speedup 1.0000x reference)
//
#include <hip/hip_runtime.h>
#include <cstdint>

// Problem constants (fixed by setup_inputs in the reference)
constexpr int Bb = 2048;
constexpr int Tt = 1024;
constexpr int Nn = 27;

__device__ __forceinline__ float rcpf(float a) { return __builtin_amdgcn_rcpf(a); }

// Fused LSTM + output projection, fp32 (no fp32 MFMA on CDNA4 -> pure VALU).
// Grid: 1024 blocks x 64 threads. Each block = ONE wave handling 2 batch rows.
// lane = bl*32 + j ; j in [0,27) = hidden unit, j in [27,32) idle pad.
// All weights register-resident (252 VGPRs of weights/lane). h and x rows live
// in tiny double-buffered LDS lines read via wave-broadcast ds_read_b128.
// Single-wave block => wave-synchronous, zero __syncthreads in the T loop;
// ordering is guaranteed by in-order DS + wave_barrier() scheduler fences.
__global__ __launch_bounds__(64, 1) void lstm_fused_kernel(
    const float* __restrict__ x,      // [B,T,N]
    const float* __restrict__ h0,     // [B,N]
    const float* __restrict__ c0,     // [B,N]
    const float* __restrict__ W_ih,   // [4N,N] gate order i,f,g,o
    const float* __restrict__ W_hh,   // [4N,N]
    const float* __restrict__ b_ih,   // [4N]
    const float* __restrict__ b_hh,   // [4N]
    const float* __restrict__ W_out,  // [N,N]
    const float* __restrict__ b_out,  // [N]
    float* __restrict__ out,          // [B,T,N]
    float* __restrict__ hn,           // [B,N]
    float* __restrict__ cn)           // [B,N]
{
    const int tid = threadIdx.x;          // 0..63
    const int bl  = tid >> 5;             // local batch 0..1
    const int j   = tid & 31;             // unit lane
    const bool act = (j < Nn);
    const int jj  = act ? j : (Nn - 1);   // clamped for safe weight loads
    const int bg  = (int)blockIdx.x * 2 + bl;   // global batch row

    // double-buffered per-batch rows; 32-wide (27 used + zeroed pad)
    __shared__ __align__(16) float xbuf[2][2][32];
    __shared__ __align__(16) float hbuf[2][2][32];

    // ---- weight rows into registers (zero-padded to k=28) ----
    float wih[4][28], whh[4][28], wout[28];
#pragma unroll
    for (int g = 0; g < 4; ++g) {
#pragma unroll
        for (int k = 0; k < 28; ++k) {
            wih[g][k] = (k < Nn) ? W_ih[(g * Nn + jj) * Nn + k] : 0.0f;
            whh[g][k] = (k < Nn) ? W_hh[(g * Nn + jj) * Nn + k] : 0.0f;
        }
    }
#pragma unroll
    for (int k = 0; k < 28; ++k)
        wout[k] = (k < Nn) ? W_out[jj * Nn + k] : 0.0f;

    const float bz0 = b_ih[0 * Nn + jj] + b_hh[0 * Nn + jj];
    const float bz1 = b_ih[1 * Nn + jj] + b_hh[1 * Nn + jj];
    const float bz2 = b_ih[2 * Nn + jj] + b_hh[2 * Nn + jj];
    const float bz3 = b_ih[3 * Nn + jj] + b_hh[3 * Nn + jj];
    const float bo  = b_out[jj];

    float c  = c0[(size_t)bg * Nn + jj];
    float hv = h0[(size_t)bg * Nn + jj];

    const float* xrow = x   + (size_t)bg * Tt * Nn + jj;  // element j of x[bg][t][:]
    float*       orow = out + (size_t)bg * Tt * Nn + j;

    // prologue: publish h0 and x[0]; prefetch x[1] into a register
    hbuf[0][bl][j] = act ? hv : 0.0f;
    xbuf[0][bl][j] = act ? xrow[0] : 0.0f;
    __builtin_amdgcn_wave_barrier();
    float xn1 = act ? xrow[Nn] : 0.0f;   // x[t=1]

#pragma unroll 2
    for (int t = 0; t < Tt; ++t) {
        const int cur = t & 1;
        const int nxt = cur ^ 1;

        // 1. publish x[t+1] (register loaded a full iteration ago)
        xbuf[nxt][bl][j] = act ? xn1 : 0.0f;
        __builtin_amdgcn_wave_barrier();

        // 2. issue global prefetch of x[t+2] (consumed next iteration)
        int t2 = t + 2; t2 = (t2 < Tt) ? t2 : (Tt - 1);
        const float xn2 = act ? xrow[(size_t)t2 * Nn] : 0.0f;

        // 3. issue ALL LDS reads up front: 7 h-quads + 7 x-quads.
        //    h latency hides under the x-FMA block below (~224 issue cycles).
        const float4* hq = (const float4*)(&hbuf[cur][bl][0]);
        const float4* xq = (const float4*)(&xbuf[cur][bl][0]);
        const float4 h0q = hq[0], h1q = hq[1], h2q = hq[2], h3q = hq[3],
                     h4q = hq[4], h5q = hq[5], h6q = hq[6];
        const float4 x0q = xq[0], x1q = xq[1], x2q = xq[2], x3q = xq[3],
                     x4q = xq[4], x5q = xq[5], x6q = xq[6];

        float z0 = bz0, z1 = bz1, z2 = bz2, z3 = bz3;
        float oacc = bo;

        // 4. x contribution: z += W_ih * x[t]   (112 FMA)
        {
            const float4 xv[7] = {x0q, x1q, x2q, x3q, x4q, x5q, x6q};
#pragma unroll
            for (int q = 0; q < 7; ++q) {
                const float4 v = xv[q];
                z0 = fmaf(wih[0][4*q+0], v.x, z0); z0 = fmaf(wih[0][4*q+1], v.y, z0);
                z0 = fmaf(wih[0][4*q+2], v.z, z0); z0 = fmaf(wih[0][4*q+3], v.w, z0);
                z1 = fmaf(wih[1][4*q+0], v.x, z1); z1 = fmaf(wih[1][4*q+1], v.y, z1);
                z1 = fmaf(wih[1][4*q+2], v.z, z1); z1 = fmaf(wih[1][4*q+3], v.w, z1);
                z2 = fmaf(wih[2][4*q+0], v.x, z2); z2 = fmaf(wih[2][4*q+1], v.y, z2);
                z2 = fmaf(wih[2][4*q+2], v.z, z2); z2 = fmaf(wih[2][4*q+3], v.w, z2);
                z3 = fmaf(wih[3][4*q+0], v.x, z3); z3 = fmaf(wih[3][4*q+1], v.y, z3);
                z3 = fmaf(wih[3][4*q+2], v.z, z3); z3 = fmaf(wih[3][4*q+3], v.w, z3);
            }
        }

        // 5. h contribution z += W_hh*h[t]; fused out[t-1] = W_out*h[t] (140 FMA)
        {
            const float4 hv4[7] = {h0q, h1q, h2q, h3q, h4q, h5q, h6q};
#pragma unroll
            for (int q = 0; q < 7; ++q) {
                const float4 v = hv4[q];
                z0 = fmaf(whh[0][4*q+0], v.x, z0); z0 = fmaf(whh[0][4*q+1], v.y, z0);
                z0 = fmaf(whh[0][4*q+2], v.z, z0); z0 = fmaf(whh[0][4*q+3], v.w, z0);
                z1 = fmaf(whh[1][4*q+0], v.x, z1); z1 = fmaf(whh[1][4*q+1], v.y, z1);
                z1 = fmaf(whh[1][4*q+2], v.z, z1); z1 = fmaf(whh[1][4*q+3], v.w, z1);
                z2 = fmaf(whh[2][4*q+0], v.x, z2); z2 = fmaf(whh[2][4*q+1], v.y, z2);
                z2 = fmaf(whh[2][4*q+2], v.z, z2); z2 = fmaf(whh[2][4*q+3], v.w, z2);
                z3 = fmaf(whh[3][4*q+0], v.x, z3); z3 = fmaf(whh[3][4*q+1], v.y, z3);
                z3 = fmaf(whh[3][4*q+2], v.z, z3); z3 = fmaf(whh[3][4*q+3], v.w, z3);
                oacc = fmaf(wout[4*q+0], v.x, oacc); oacc = fmaf(wout[4*q+1], v.y, oacc);
                oacc = fmaf(wout[4*q+2], v.z, oacc); oacc = fmaf(wout[4*q+3], v.w, oacc);
            }
        }

        // 6. store out[t-1] (projection of h published last step)
        if (t > 0 && act) orow[(size_t)(t - 1) * Nn] = oacc;

        // 7. gates (i,f,g,o) + cell/state update. Overflow-safe forms.
        const float e0 = __expf(-z0);
        const float e1 = __expf(-z1);
        const float e2 = __expf(2.0f * z2);
        const float e3 = __expf(-z3);
        const float ig = rcpf(1.0f + e0);
        const float fg = rcpf(1.0f + e1);
        const float gg = 1.0f - 2.0f * rcpf(1.0f + e2);   // tanh(z2)
        const float og = rcpf(1.0f + e3);
        c = fmaf(fg, c, ig * gg);
        const float tc = 1.0f - 2.0f * rcpf(1.0f + __expf(2.0f * c));  // tanh(c)
        hv = og * tc;

        // 8. publish h[t+1]
        hbuf[nxt][bl][j] = act ? hv : 0.0f;
        __builtin_amdgcn_wave_barrier();
        xn1 = xn2;
    }

    // epilogue: out[T-1] projection + final states
    {
        float oacc = bo;
        const float4* hq = (const float4*)(&hbuf[Tt & 1][bl][0]);
#pragma unroll
        for (int q = 0; q < 7; ++q) {
            const float4 v = hq[q];
            oacc = fmaf(wout[4*q+0], v.x, oacc); oacc = fmaf(wout[4*q+1], v.y, oacc);
            oacc = fmaf(wout[4*q+2], v.z, oacc); oacc = fmaf(wout[4*q+3], v.w, oacc);
        }
        if (act) {
            orow[(size_t)(Tt - 1) * Nn] = oacc;
            hn[(size_t)bg * Nn + j] = hv;
            cn[(size_t)bg * Nn + j] = c;
        }
    }
}

extern "C" void kernel_launch(void* const* d_in, const int* in_sizes, int n_in,
                              void* d_out, int out_size, void* d_ws, size_t ws_size,
                              hipStream_t stream) {
    const float* x     = (const float*)d_in[0];
    const float* h0    = (const float*)d_in[1];
    const float* c0    = (const float*)d_in[2];
    const float* W_ih  = (const float*)d_in[3];
    const float* W_hh  = (const float*)d_in[4];
    const float* b_ih  = (const float*)d_in[5];
    const float* b_hh  = (const float*)d_in[6];
    const float* W_out = (const float*)d_in[7];
    const float* b_out = (const float*)d_in[8];

    float* out = (float*)d_out;                          // [B,T,N]
    float* hn  = out + (size_t)Bb * Tt * Nn;             // [1,B,N]
    float* cn  = hn + (size_t)Bb * Nn;                   // [1,B,N]

    lstm_fused_kernel<<<dim3(Bb / 2), dim3(64), 0, stream>>>(
        x, h0, c0, W_ih, W_hh, b_ih, b_hh, W_out, b_out, out, hn, cn);
}

// Round 3
// 951.735 us; speedup vs baseline: 1.1112x; 1.1112x over previous
//
#include <hip/hip_runtime.h>
#include <cstdint>

// Problem constants (fixed by setup_inputs in the reference)
constexpr int Bb = 2048;
constexpr int Tt = 1024;
constexpr int Nn = 27;
constexpr int KH = 16;   // padded k-half handled by each lane (2 halves cover k=0..31)

__device__ __forceinline__ float rcpf(float a) { return __builtin_amdgcn_rcpf(a); }

// Fused LSTM + output projection, fp32 (no fp32 MFMA on CDNA4 -> pure VALU).
//
// v3: split-K layout. Grid: 2048 single-wave blocks, ONE batch row per wave
// (2 waves/SIMD for latency hiding). lane = half*32 + j:
//   j    = hidden unit (j<27 active)
//   half = which 16-wide k-chunk of the dot products this lane accumulates
// Weight rows per lane: 4x16 (W_ih) + 4x16 (W_hh) + 16 (W_out) = 144 VGPRs --
// fits the 256 arch-VGPR file (v2 needed 292 -> AGPR overflow -> one move per
// FMA, measured as 1575 VALU-cyc/step vs 600 ideal).
// Per step: partial z in each half, combined with __shfl_xor(.,32).
// x-contribution for step t+1 (zx) is computed during step t's serial gate
// tail (it only depends on xbuf, published a step earlier from registers).
__global__ __launch_bounds__(64, 2) void lstm_fused_kernel(
    const float* __restrict__ x,      // [B,T,N]
    const float* __restrict__ h0,     // [B,N]
    const float* __restrict__ c0,     // [B,N]
    const float* __restrict__ W_ih,   // [4N,N] gate order i,f,g,o
    const float* __restrict__ W_hh,   // [4N,N]
    const float* __restrict__ b_ih,   // [4N]
    const float* __restrict__ b_hh,   // [4N]
    const float* __restrict__ W_out,  // [N,N]
    const float* __restrict__ b_out,  // [N]
    float* __restrict__ out,          // [B,T,N]
    float* __restrict__ hn,           // [B,N]
    float* __restrict__ cn)           // [B,N]
{
    const int lane = threadIdx.x;         // 0..63
    const int j    = lane & 31;           // hidden unit
    const int half = lane >> 5;           // k-chunk index
    const int k0   = half * KH;           // first k of this lane's chunk
    const bool act = (j < Nn);
    const bool pub = (lane < Nn);         // half-0 active lanes: publish + store
    const int jj   = act ? j : (Nn - 1);  // clamped for safe weight loads
    const int bg   = blockIdx.x;          // batch row

    // one row per block; 32-wide (27 used + zeroed pad). double-buffered.
    __shared__ __align__(16) float xbuf[2][32];
    __shared__ __align__(16) float hbuf[2][32];

    // ---- weight chunks into registers (zero-padded for k>=27) ----
    float wih[4][KH], whh[4][KH], wout[KH];
#pragma unroll
    for (int g = 0; g < 4; ++g) {
#pragma unroll
        for (int kk = 0; kk < KH; ++kk) {
            const int k = k0 + kk;
            wih[g][kk] = (k < Nn) ? W_ih[(g * Nn + jj) * Nn + k] : 0.0f;
            whh[g][kk] = (k < Nn) ? W_hh[(g * Nn + jj) * Nn + k] : 0.0f;
        }
    }
#pragma unroll
    for (int kk = 0; kk < KH; ++kk) {
        const int k = k0 + kk;
        wout[kk] = (k < Nn) ? W_out[jj * Nn + k] : 0.0f;
    }

    // biases live only in half 0 (the cross-half reduction adds them once)
    const float bz0 = (half == 0) ? b_ih[0 * Nn + jj] + b_hh[0 * Nn + jj] : 0.0f;
    const float bz1 = (half == 0) ? b_ih[1 * Nn + jj] + b_hh[1 * Nn + jj] : 0.0f;
    const float bz2 = (half == 0) ? b_ih[2 * Nn + jj] + b_hh[2 * Nn + jj] : 0.0f;
    const float bz3 = (half == 0) ? b_ih[3 * Nn + jj] + b_hh[3 * Nn + jj] : 0.0f;
    const float bo  = (half == 0) ? b_out[jj] : 0.0f;

    float c  = c0[(size_t)bg * Nn + jj];   // cell state (duplicated across halves)
    float hv = h0[(size_t)bg * Nn + jj];   // hidden state (duplicated)

    const float* xrow = x   + (size_t)bg * Tt * Nn;
    float*       orow = out + (size_t)bg * Tt * Nn;

    // prologue: publish h0 + x[0]; zero the pads of BOTH buffers once
    if (lane < 32) {
        xbuf[0][j] = act ? xrow[j] : 0.0f;
        hbuf[0][j] = act ? hv : 0.0f;
        xbuf[1][j] = 0.0f;
        hbuf[1][j] = 0.0f;
    }
    __builtin_amdgcn_wave_barrier();

    // x prefetch pipeline, distance 2 iterations (~800 cyc > HBM latency)
    float xn1 = pub ? xrow[1 * Nn + j] : 0.0f;   // x[t=1]
    float xn2 = pub ? xrow[2 * Nn + j] : 0.0f;   // x[t=2]

    // zx = bias + W_ih * x[0]  (x-contribution for step 0)
    float zx0, zx1, zx2, zx3;
    {
        const float4* xq = (const float4*)(&xbuf[0][k0]);
        const float4 v0 = xq[0], v1 = xq[1], v2 = xq[2], v3 = xq[3];
        const float4 xv[4] = {v0, v1, v2, v3};
        zx0 = bz0; zx1 = bz1; zx2 = bz2; zx3 = bz3;
#pragma unroll
        for (int q = 0; q < 4; ++q) {
            const float4 v = xv[q];
            zx0 = fmaf(wih[0][4*q+0], v.x, zx0); zx0 = fmaf(wih[0][4*q+1], v.y, zx0);
            zx0 = fmaf(wih[0][4*q+2], v.z, zx0); zx0 = fmaf(wih[0][4*q+3], v.w, zx0);
            zx1 = fmaf(wih[1][4*q+0], v.x, zx1); zx1 = fmaf(wih[1][4*q+1], v.y, zx1);
            zx1 = fmaf(wih[1][4*q+2], v.z, zx1); zx1 = fmaf(wih[1][4*q+3], v.w, zx1);
            zx2 = fmaf(wih[2][4*q+0], v.x, zx2); zx2 = fmaf(wih[2][4*q+1], v.y, zx2);
            zx2 = fmaf(wih[2][4*q+2], v.z, zx2); zx2 = fmaf(wih[2][4*q+3], v.w, zx2);
            zx3 = fmaf(wih[3][4*q+0], v.x, zx3); zx3 = fmaf(wih[3][4*q+1], v.y, zx3);
            zx3 = fmaf(wih[3][4*q+2], v.z, zx3); zx3 = fmaf(wih[3][4*q+3], v.w, zx3);
        }
    }

#pragma unroll 2
    for (int t = 0; t < Tt; ++t) {
        const int cur = t & 1;
        const int nxt = cur ^ 1;

        // 1. publish x[t+1] (register loaded 2 iterations ago)
        if (pub) xbuf[nxt][j] = xn1;
        __builtin_amdgcn_wave_barrier();

        // 2. issue global prefetch of x[t+3]
        int t3 = t + 3; t3 = (t3 < Tt) ? t3 : (Tt - 1);
        const float xnew = pub ? xrow[(size_t)t3 * Nn + j] : 0.0f;

        // 3. h[t] chunk from LDS (wave-broadcast per half, conflict-free)
        const float4* hq = (const float4*)(&hbuf[cur][k0]);
        const float4 h0q = hq[0], h1q = hq[1], h2q = hq[2], h3q = hq[3];

        // 4. z = zx + W_hh*h ; fused out[t-1] partial = W_out*h   (80 FMA)
        float z0 = zx0, z1 = zx1, z2 = zx2, z3 = zx3;
        float oacc = bo;
        {
            const float4 hv4[4] = {h0q, h1q, h2q, h3q};
#pragma unroll
            for (int q = 0; q < 4; ++q) {
                const float4 v = hv4[q];
                z0 = fmaf(whh[0][4*q+0], v.x, z0); z0 = fmaf(whh[0][4*q+1], v.y, z0);
                z0 = fmaf(whh[0][4*q+2], v.z, z0); z0 = fmaf(whh[0][4*q+3], v.w, z0);
                z1 = fmaf(whh[1][4*q+0], v.x, z1); z1 = fmaf(whh[1][4*q+1], v.y, z1);
                z1 = fmaf(whh[1][4*q+2], v.z, z1); z1 = fmaf(whh[1][4*q+3], v.w, z1);
                z2 = fmaf(whh[2][4*q+0], v.x, z2); z2 = fmaf(whh[2][4*q+1], v.y, z2);
                z2 = fmaf(whh[2][4*q+2], v.z, z2); z2 = fmaf(whh[2][4*q+3], v.w, z2);
                z3 = fmaf(whh[3][4*q+0], v.x, z3); z3 = fmaf(whh[3][4*q+1], v.y, z3);
                z3 = fmaf(whh[3][4*q+2], v.z, z3); z3 = fmaf(whh[3][4*q+3], v.w, z3);
                oacc = fmaf(wout[4*q+0], v.x, oacc); oacc = fmaf(wout[4*q+1], v.y, oacc);
                oacc = fmaf(wout[4*q+2], v.z, oacc); oacc = fmaf(wout[4*q+3], v.w, oacc);
            }
        }

        // 5. combine the two k-halves
        z0 += __shfl_xor(z0, 32);
        z1 += __shfl_xor(z1, 32);
        z2 += __shfl_xor(z2, 32);
        z3 += __shfl_xor(z3, 32);
        oacc += __shfl_xor(oacc, 32);

        // 6. store out[t-1] (projection of h published last step)
        if (t > 0 && pub) orow[(size_t)(t - 1) * Nn + j] = oacc;

        // 7. gates (i,f,g,o) + cell/state update (serial tail ...)
        const float e0 = __expf(-z0);
        const float e1 = __expf(-z1);
        const float e2 = __expf(2.0f * z2);
        const float e3 = __expf(-z3);
        const float ig = rcpf(1.0f + e0);
        const float fg = rcpf(1.0f + e1);
        const float gg = 1.0f - 2.0f * rcpf(1.0f + e2);   // tanh(z2)
        const float og = rcpf(1.0f + e3);
        c = fmaf(fg, c, ig * gg);
        const float tc = 1.0f - 2.0f * rcpf(1.0f + __expf(2.0f * c));  // tanh(c)
        hv = og * tc;

        // 8. ... which the scheduler fills with next step's x-contribution
        //    (depends only on xbuf[nxt], published at the top of this iter)
        {
            const float4* xq = (const float4*)(&xbuf[nxt][k0]);
            const float4 v0 = xq[0], v1 = xq[1], v2 = xq[2], v3 = xq[3];
            const float4 xv[4] = {v0, v1, v2, v3};
            zx0 = bz0; zx1 = bz1; zx2 = bz2; zx3 = bz3;
#pragma unroll
            for (int q = 0; q < 4; ++q) {
                const float4 v = xv[q];
                zx0 = fmaf(wih[0][4*q+0], v.x, zx0); zx0 = fmaf(wih[0][4*q+1], v.y, zx0);
                zx0 = fmaf(wih[0][4*q+2], v.z, zx0); zx0 = fmaf(wih[0][4*q+3], v.w, zx0);
                zx1 = fmaf(wih[1][4*q+0], v.x, zx1); zx1 = fmaf(wih[1][4*q+1], v.y, zx1);
                zx1 = fmaf(wih[1][4*q+2], v.z, zx1); zx1 = fmaf(wih[1][4*q+3], v.w, zx1);
                zx2 = fmaf(wih[2][4*q+0], v.x, zx2); zx2 = fmaf(wih[2][4*q+1], v.y, zx2);
                zx2 = fmaf(wih[2][4*q+2], v.z, zx2); zx2 = fmaf(wih[2][4*q+3], v.w, zx2);
                zx3 = fmaf(wih[3][4*q+0], v.x, zx3); zx3 = fmaf(wih[3][4*q+1], v.y, zx3);
                zx3 = fmaf(wih[3][4*q+2], v.z, zx3); zx3 = fmaf(wih[3][4*q+3], v.w, zx3);
            }
        }

        // 9. publish h[t]
        if (pub) hbuf[nxt][j] = hv;
        __builtin_amdgcn_wave_barrier();
        xn1 = xn2;
        xn2 = xnew;
    }

    // epilogue: out[T-1] projection + final states (h in hbuf[Tt&1 == 0])
    {
        const float4* hq = (const float4*)(&hbuf[0][k0]);
        const float4 h0q = hq[0], h1q = hq[1], h2q = hq[2], h3q = hq[3];
        const float4 hv4[4] = {h0q, h1q, h2q, h3q};
        float oacc = bo;
#pragma unroll
        for (int q = 0; q < 4; ++q) {
            const float4 v = hv4[q];
            oacc = fmaf(wout[4*q+0], v.x, oacc); oacc = fmaf(wout[4*q+1], v.y, oacc);
            oacc = fmaf(wout[4*q+2], v.z, oacc); oacc = fmaf(wout[4*q+3], v.w, oacc);
        }
        oacc += __shfl_xor(oacc, 32);
        if (pub) {
            orow[(size_t)(Tt - 1) * Nn + j] = oacc;
            hn[(size_t)bg * Nn + j] = hv;
            cn[(size_t)bg * Nn + j] = c;
        }
    }
}

extern "C" void kernel_launch(void* const* d_in, const int* in_sizes, int n_in,
                              void* d_out, int out_size, void* d_ws, size_t ws_size,
                              hipStream_t stream) {
    const float* x     = (const float*)d_in[0];
    const float* h0    = (const float*)d_in[1];
    const float* c0    = (const float*)d_in[2];
    const float* W_ih  = (const float*)d_in[3];
    const float* W_hh  = (const float*)d_in[4];
    const float* b_ih  = (const float*)d_in[5];
    const float* b_hh  = (const float*)d_in[6];
    const float* W_out = (const float*)d_in[7];
    const float* b_out = (const float*)d_in[8];

    float* out = (float*)d_out;                          // [B,T,N]
    float* hn  = out + (size_t)Bb * Tt * Nn;             // [1,B,N]
    float* cn  = hn + (size_t)Bb * Nn;                   // [1,B,N]

    lstm_fused_kernel<<<dim3(Bb), dim3(64), 0, stream>>>(
        x, h0, c0, W_ih, W_hh, b_ih, b_hh, W_out, b_out, out, hn, cn);
}